// Round 3
// baseline (927.695 us; speedup 1.0000x reference)
//
#include <hip/hip_runtime.h>

// EquiConv fused MFMA kernel for MI355X (gfx950) — round 3.
// Key change vs R2: B-traffic per edge is the structural limit (16x16x32 needs
// 1KB B per MFMA -> 129 TB/s from L2 at full rate, 3.7x over ceiling).
// Fix: T=2 M-tile reuse per wave (B-frag used twice from registers) + B fed
// from LDS (69 TB/s) via a global_load_lds ring (56 x 24KB chunks, 4 slots,
// depth-3 prefetch). 157 blocks x 4 waves x 32 edges = uniform 1 block/CU.
// Fragment layouts per learn_hip m89/m120 (verified R1/R2).

#define E_TOT 20000

typedef __attribute__((ext_vector_type(8))) short short8;
typedef __attribute__((ext_vector_type(4))) float f32x4;
typedef __attribute__((ext_vector_type(2))) __bf16 bf16x2;

// ---- packed-B stream: 56 chunks x 12288 ushort (24KB); frag = 512 ushort ----
// chunks 0..31 SS (2u/chunk), 32..39 VV (4u), 40..47 SV (8u, frags16-23 pad),
// 48..55 VS (4u, frags 16-23 pad). FC sections appended after the stream.
#define CHUNK_USH 12288
#define N_CHUNKS 56
#define VV_C0 32
#define SV_C0 40
#define VS_C0 48
#define STREAM_USH (N_CHUNKS*CHUNK_USH)   // 688128
#define F1_OFF STREAM_USH
#define F2_OFF (STREAM_USH+8192)
#define F3_OFF (STREAM_USH+12288)
#define WS_TOTAL (STREAM_USH+18432)       // 706560 ushort = 1.38 MB

__device__ __forceinline__ unsigned short f2b(float f){
  return __builtin_bit_cast(unsigned short, (__bf16)f);
}
__device__ __forceinline__ unsigned f2b2(float lo, float hi){
  bf16x2 t; t[0] = (__bf16)lo; t[1] = (__bf16)hi;
  return __builtin_bit_cast(unsigned, t);
}
__device__ __forceinline__ float b2f(unsigned short h){
  return __uint_as_float(((unsigned)h) << 16);
}
__device__ __forceinline__ f32x4 mfma16(short8 a, short8 b, f32x4 c){
  return __builtin_amdgcn_mfma_f32_16x16x32_bf16(a, b, c, 0, 0, 0);
}
union U8 { short8 v; unsigned u[4]; };
__device__ __forceinline__ float silu_f(float x){ return x/(1.f+__expf(-x)); }
__device__ __forceinline__ float sigm_f(float x){ return 1.f/(1.f+__expf(-x)); }

#define PACK8(a, s, x) \
  a.u[0]=f2b2((s)*(x)[0],(s)*(x)[1]); a.u[1]=f2b2((s)*(x)[2],(s)*(x)[3]); \
  a.u[2]=f2b2((s)*(x)[4],(s)*(x)[5]); a.u[3]=f2b2((s)*(x)[6],(s)*(x)[7]);

// ---------------- prep: repack weights into stream order ----------------
__global__ void prep_weights(const float* __restrict__ ss_s, const float* __restrict__ vv_s,
                             const float* __restrict__ ss_g, const float* __restrict__ vv_g,
                             const float* __restrict__ sv,   const float* __restrict__ vs,
                             const float* __restrict__ w1,   const float* __restrict__ w2,
                             const float* __restrict__ w3,   unsigned short* __restrict__ wsb)
{
  int idx = blockIdx.x * 256 + threadIdx.x;
  if (idx >= WS_TOTAL) return;
  const float A_SC  = 0.013975424859373686f;                       // 1/sqrt(S*S+V*V)
  const float A_VV  = (float)(0.013975424859373686 * 0.5773502691896258);
  const float A_VEC = 0.015625f;                                   // 1/sqrt(2*S*V)
  float v = 0.f;
  if (idx < STREAM_USH){
    int chunk = idx / CHUNK_USH;
    int rem = idx - chunk*CHUNK_USH;
    int frag = rem >> 9;
    int q = rem & 511;
    int lane = q >> 3, j = q & 7;
    int kl = ((lane >> 4) << 3) + j;      // k_local in [0,32)
    int n16 = lane & 15;
    if (chunk < VV_C0){                   // SS: u = 2*chunk + e
      int e = frag / 12, lf = frag - e*12;
      int u = 2*chunk + e, half = lf / 6, t = lf - half*6;
      int k = u*64 + half*32 + kl, n = t*16 + n16;
      v = A_SC * (n < 64 ? ss_s[k*64+n] : ss_g[k*32+(n-64)]);
    } else if (chunk < SV_C0){            // VV: u = (chunk-32)*4 + e
      int e = frag / 6, t = frag - e*6;
      int u = (chunk - VV_C0)*4 + e;
      int k = u*32 + kl, n = t*16 + n16;
      v = A_VV * (n < 64 ? vv_s[k*64+n] : vv_g[k*32+(n-64)]);
    } else if (chunk < VS_C0){            // SV: u = (chunk-40)*8 + e
      if (frag < 16){
        int e = frag >> 1, t = frag & 1;
        int u = (chunk - SV_C0)*8 + e;
        v = A_VEC * sv[(u*32 + kl)*32 + t*16 + n16];
      }
    } else {                              // VS: u = (chunk-48)*4 + e
      if (frag < 16){
        int e = frag >> 2, ss = frag & 3, h = ss >> 1, t = ss & 1;
        int u = (chunk - VS_C0)*4 + e;
        v = A_VEC * vs[(u*64 + h*32 + kl)*32 + t*16 + n16];
      }
    }
  } else {
    int f = idx - F1_OFF;
    int j = f & 7, lane = (f >> 3) & 63;
    int n16 = lane & 15, kq = ((lane >> 4) << 3) + j;
    if (f < 8192){                        // FC1: NT=4
      int t = (f >> 9) & 3, c = f >> 11;
      v = w1[(c*32+kq)*64 + t*16 + n16];
    } else if (f < 12288){                // FC2: NT=4
      int g = f - 8192;
      int t = (g >> 9) & 3, c = g >> 11;
      v = w2[(c*32+kq)*64 + t*16 + n16];
    } else {                              // FC3: NT=6
      int g = f - 12288;
      int t = (g >> 9) % 6, c = g / 3072;
      v = w3[(c*32+kq)*96 + t*16 + n16];
    }
  }
  wsb[idx] = f2b(v);
}

// ---------------- main fused kernel ----------------
__global__ __launch_bounds__(256, 1)
void equiconv_main(const float* __restrict__ fea1,
                   const float* __restrict__ fea2,
                   const float* __restrict__ few,
                   const float* __restrict__ fb1,
                   const float* __restrict__ fb2,
                   const float* __restrict__ fb3,
                   const unsigned short* __restrict__ wsb,
                   float* __restrict__ out)
{
  __shared__ __align__(16) unsigned short ring[4*CHUNK_USH];  // 96 KB
  __shared__ __align__(16) unsigned short x1s[128][65];
  __shared__ __align__(16) unsigned short x1v[128][97];
  __shared__ __align__(16) unsigned short h1[4][16][72];
  __shared__ __align__(16) unsigned short h2[4][16][72];

  const int tid  = threadIdx.x;
  const int lane = tid & 63, wv = tid >> 6;
  const int ln   = lane & 15, quad = lane >> 4, q8 = quad << 3;
  const int ebase = blockIdx.x << 7;   // 157 blocks x 128 edges (last clamped)

  // ---- issue one 24KB chunk: 6 x global_load_lds(16B) per thread ----
  auto issue_chunk = [&](int cn){
    const unsigned short* g = wsb + (size_t)cn*CHUNK_USH + wv*512 + lane*8;
    unsigned short* l = &ring[(cn & 3)*CHUNK_USH + wv*512];
    #pragma unroll
    for (int q = 0; q < 6; q++)
      __builtin_amdgcn_global_load_lds(
        (const __attribute__((address_space(1))) unsigned int*)(g + q*2048),
        (__attribute__((address_space(3))) unsigned int*)(l + q*2048),
        16, 0, 0);
  };
  auto ringstep = [&](int ci){
    __syncthreads();                 // drain (compiler emits vmcnt(0)) + slot-free
    if (ci + 3 < N_CHUNKS) issue_chunk(ci + 3);
  };

  // ---- stage x1 (128 edges) into LDS as bf16 ----
  for (int it = tid; it < 5120; it += 256){
    int row = it / 40, seg = it - row*40;
    int src = ebase + row; if (src > E_TOT-1) src = E_TOT-1;
    float4 v1 = *(const float4*)(fea1 + (size_t)src*160 + seg*4);
    const float* p1 = (const float*)&v1;
    int c0 = seg*4;
    #pragma unroll
    for (int jj = 0; jj < 4; jj++){
      int col = c0 + jj;
      if (col < 64) x1s[row][col] = f2b(p1[jj]);
      else          x1v[row][col-64] = f2b(p1[jj]);
    }
  }

  // prime ring with chunks 0..2
  issue_chunk(0); issue_chunk(1); issue_chunk(2);

  // ---- hoist per-lane x2 fragments for both sub-tiles (direct from global) ----
  float xe[2][8], xo[2][8], y0[2][8], y1[2][8], y2[2][8];
  #pragma unroll
  for (int s = 0; s < 2; s++){
    int rg = ebase + wv*32 + s*16 + ln; if (rg > E_TOT-1) rg = E_TOT-1;
    const float* p = fea2 + (size_t)rg*160;
    float4 a0 = *(const float4*)(p + q8);
    float4 a1 = *(const float4*)(p + q8 + 4);
    float4 b0 = *(const float4*)(p + 32 + q8);
    float4 b1 = *(const float4*)(p + 36 + q8);
    xe[s][0]=a0.x; xe[s][1]=a0.y; xe[s][2]=a0.z; xe[s][3]=a0.w;
    xe[s][4]=a1.x; xe[s][5]=a1.y; xe[s][6]=a1.z; xe[s][7]=a1.w;
    xo[s][0]=b0.x; xo[s][1]=b0.y; xo[s][2]=b0.z; xo[s][3]=b0.w;
    xo[s][4]=b1.x; xo[s][5]=b1.y; xo[s][6]=b1.z; xo[s][7]=b1.w;
    float yb[24];
    const float* py = p + 64 + q8*3;
    #pragma unroll
    for (int t = 0; t < 12; t++){
      float2 f2v = *(const float2*)(py + 2*t);
      yb[2*t] = f2v.x; yb[2*t+1] = f2v.y;
    }
    #pragma unroll
    for (int j = 0; j < 8; j++){
      y0[s][j] = yb[3*j]; y1[s][j] = yb[3*j+1]; y2[s][j] = yb[3*j+2];
    }
  }

  const int rows0 = wv*32 + ln, rows1 = wv*32 + 16 + ln;  // LDS x1 rows per sub
  const f32x4 z4 = {0.f,0.f,0.f,0.f};
  f32x4 accS[2][6] = {{z4,z4,z4,z4,z4,z4},{z4,z4,z4,z4,z4,z4}};
  f32x4 accV[2][3][2] = {{{z4,z4},{z4,z4},{z4,z4}},{{z4,z4},{z4,z4},{z4,z4}}};

  // ================= SS: chunks 0..31, u = 2p+e =================
  #pragma unroll 1
  for (int p = 0; p < 32; p++){
    ringstep(p);
    const int slot = (p & 3)*CHUNK_USH;
    #pragma unroll
    for (int e = 0; e < 2; e++){
      int u = 2*p + e;
      float s0 = b2f(x1s[rows0][u]);
      float s1 = b2f(x1s[rows1][u]);
      const int fb = slot + e*12*512;
      U8 a0, a1;
      PACK8(a0, s0, xe[0]); PACK8(a1, s1, xe[1]);
      #pragma unroll
      for (int t = 0; t < 6; t++){
        short8 bb = *(const short8*)&ring[fb + t*512 + lane*8];
        accS[0][t] = mfma16(a0.v, bb, accS[0][t]);
        accS[1][t] = mfma16(a1.v, bb, accS[1][t]);
      }
      PACK8(a0, s0, xo[0]); PACK8(a1, s1, xo[1]);
      #pragma unroll
      for (int t = 0; t < 6; t++){
        short8 bb = *(const short8*)&ring[fb + (6+t)*512 + lane*8];
        accS[0][t] = mfma16(a0.v, bb, accS[0][t]);
        accS[1][t] = mfma16(a1.v, bb, accS[1][t]);
      }
    }
  }
  // ================= VV: chunks 32..39, u = 4q+e =================
  #pragma unroll 1
  for (int qc = 0; qc < 8; qc++){
    ringstep(VV_C0 + qc);
    const int slot = ((VV_C0 + qc) & 3)*CHUNK_USH;
    #pragma unroll
    for (int e = 0; e < 4; e++){
      int u = qc*4 + e;
      U8 a[2];
      #pragma unroll
      for (int s = 0; s < 2; s++){
        int rr = s ? rows1 : rows0;
        float c0 = b2f(x1v[rr][u*3+0]);
        float c1 = b2f(x1v[rr][u*3+1]);
        float c2 = b2f(x1v[rr][u*3+2]);
        float pv[8];
        #pragma unroll
        for (int j = 0; j < 8; j++)
          pv[j] = c0*y0[s][j] + c1*y1[s][j] + c2*y2[s][j];
        a[s].u[0]=f2b2(pv[0],pv[1]); a[s].u[1]=f2b2(pv[2],pv[3]);
        a[s].u[2]=f2b2(pv[4],pv[5]); a[s].u[3]=f2b2(pv[6],pv[7]);
      }
      const int fb = slot + e*6*512;
      #pragma unroll
      for (int t = 0; t < 6; t++){
        short8 bb = *(const short8*)&ring[fb + t*512 + lane*8];
        accS[0][t] = mfma16(a[0].v, bb, accS[0][t]);
        accS[1][t] = mfma16(a[1].v, bb, accS[1][t]);
      }
    }
  }
  // ================= SV: chunks 40..47, u = 8r+e =================
  #pragma unroll 1
  for (int rc = 0; rc < 8; rc++){
    ringstep(SV_C0 + rc);
    const int slot = ((SV_C0 + rc) & 3)*CHUNK_USH;
    #pragma unroll
    for (int e = 0; e < 8; e++){
      int u = rc*8 + e;
      U8 a[2][3];
      {
        float s0 = b2f(x1s[rows0][u]);
        PACK8(a[0][0], s0, y0[0]); PACK8(a[0][1], s0, y1[0]); PACK8(a[0][2], s0, y2[0]);
        float s1 = b2f(x1s[rows1][u]);
        PACK8(a[1][0], s1, y0[1]); PACK8(a[1][1], s1, y1[1]); PACK8(a[1][2], s1, y2[1]);
      }
      const int fb = slot + e*2*512;
      #pragma unroll
      for (int t = 0; t < 2; t++){
        short8 bb = *(const short8*)&ring[fb + t*512 + lane*8];
        #pragma unroll
        for (int s = 0; s < 2; s++)
          #pragma unroll
          for (int i = 0; i < 3; i++)
            accV[s][i][t] = mfma16(a[s][i].v, bb, accV[s][i][t]);
      }
    }
  }
  // ================= VS: chunks 48..55, u = 4c+e =================
  #pragma unroll 1
  for (int sc = 0; sc < 8; sc++){
    ringstep(VS_C0 + sc);
    const int slot = ((VS_C0 + sc) & 3)*CHUNK_USH;
    #pragma unroll
    for (int e = 0; e < 4; e++){
      int u = sc*4 + e;
      float c0[2], c1[2], c2[2];
      c0[0] = b2f(x1v[rows0][u*3+0]); c1[0] = b2f(x1v[rows0][u*3+1]); c2[0] = b2f(x1v[rows0][u*3+2]);
      c0[1] = b2f(x1v[rows1][u*3+0]); c1[1] = b2f(x1v[rows1][u*3+1]); c2[1] = b2f(x1v[rows1][u*3+2]);
      const int fb = slot + e*4*512;
      U8 a[2][3];
      #pragma unroll
      for (int s = 0; s < 2; s++){
        PACK8(a[s][0], c0[s], xe[s]); PACK8(a[s][1], c1[s], xe[s]); PACK8(a[s][2], c2[s], xe[s]);
      }
      #pragma unroll
      for (int t = 0; t < 2; t++){
        short8 bb = *(const short8*)&ring[fb + t*512 + lane*8];
        #pragma unroll
        for (int s = 0; s < 2; s++)
          #pragma unroll
          for (int i = 0; i < 3; i++)
            accV[s][i][t] = mfma16(a[s][i].v, bb, accV[s][i][t]);
      }
      #pragma unroll
      for (int s = 0; s < 2; s++){
        PACK8(a[s][0], c0[s], xo[s]); PACK8(a[s][1], c1[s], xo[s]); PACK8(a[s][2], c2[s], xo[s]);
      }
      #pragma unroll
      for (int t = 0; t < 2; t++){
        short8 bb = *(const short8*)&ring[fb + (2+t)*512 + lane*8];
        #pragma unroll
        for (int s = 0; s < 2; s++)
          #pragma unroll
          for (int i = 0; i < 3; i++)
            accV[s][i][t] = mfma16(a[s][i].v, bb, accV[s][i][t]);
      }
    }
  }

  // ================= FC chain + epilogue, per sub-tile (wave-private) =========
  #pragma unroll 1
  for (int s = 0; s < 2; s++){
    // FC1
    f32x4 accF[4] = {z4,z4,z4,z4};
    {
      int rg = ebase + wv*32 + s*16 + ln; if (rg > E_TOT-1) rg = E_TOT-1;
      const float* fwp = few + (size_t)rg*128;
      const short8* B = (const short8*)(wsb + F1_OFF);
      #pragma unroll
      for (int c = 0; c < 4; c++){
        float4 fa  = *(const float4*)(fwp + c*32 + q8);
        float4 fbv = *(const float4*)(fwp + c*32 + q8 + 4);
        U8 a;
        a.u[0]=f2b2(fa.x,fa.y);   a.u[1]=f2b2(fa.z,fa.w);
        a.u[2]=f2b2(fbv.x,fbv.y); a.u[3]=f2b2(fbv.z,fbv.w);
        #pragma unroll
        for (int t = 0; t < 4; t++) accF[t] = mfma16(a.v, B[(c*4+t)*64 + lane], accF[t]);
      }
    }
    #pragma unroll
    for (int t = 0; t < 4; t++){
      float bb = fb1[(t<<4)+ln];
      #pragma unroll
      for (int r = 0; r < 4; r++)
        h1[wv][(quad<<2)+r][(t<<4)+ln] = f2b(silu_f(accF[t][r] + bb));
    }
    // FC2 (same-wave DS ordering: no barrier needed)
    f32x4 acc2[4] = {z4,z4,z4,z4};
    {
      const short8* B = (const short8*)(wsb + F2_OFF);
      #pragma unroll
      for (int c = 0; c < 2; c++){
        uint4 hq = *(const uint4*)&h1[wv][ln][c*32 + q8];
        U8 a; a.u[0]=hq.x; a.u[1]=hq.y; a.u[2]=hq.z; a.u[3]=hq.w;
        #pragma unroll
        for (int t = 0; t < 4; t++) acc2[t] = mfma16(a.v, B[(c*4+t)*64 + lane], acc2[t]);
      }
    }
    #pragma unroll
    for (int t = 0; t < 4; t++){
      float bb = fb2[(t<<4)+ln];
      #pragma unroll
      for (int r = 0; r < 4; r++)
        h2[wv][(quad<<2)+r][(t<<4)+ln] = f2b(silu_f(acc2[t][r] + bb));
    }
    // FC3
    f32x4 acc3[6] = {z4,z4,z4,z4,z4,z4};
    {
      const short8* B = (const short8*)(wsb + F3_OFF);
      #pragma unroll
      for (int c = 0; c < 2; c++){
        uint4 hq = *(const uint4*)&h2[wv][ln][c*32 + q8];
        U8 a; a.u[0]=hq.x; a.u[1]=hq.y; a.u[2]=hq.z; a.u[3]=hq.w;
        #pragma unroll
        for (int t = 0; t < 6; t++) acc3[t] = mfma16(a.v, B[(c*6+t)*64 + lane], acc3[t]);
      }
    }
    // epilogue (C-layout row = quad*4+r)
    #pragma unroll
    for (int r = 0; r < 4; r++){
      int eg = ebase + wv*32 + s*16 + (quad<<2) + r;
      if (eg < E_TOT){
        float* op = out + (size_t)eg*160;
        #pragma unroll
        for (int t = 0; t < 4; t++)
          op[(t<<4)+ln] = silu_f(accS[s][t][r]) * (acc3[t][r] + fb3[(t<<4)+ln]);
        #pragma unroll
        for (int tp = 0; tp < 2; tp++){
          int wc = (tp<<4) + ln;
          float f = sigm_f(accS[s][4+tp][r]) * (acc3[4+tp][r] + fb3[64+wc]);
          op[64 + wc*3 + 0] = accV[s][0][tp][r] * f;
          op[64 + wc*3 + 1] = accV[s][1][tp][r] * f;
          op[64 + wc*3 + 2] = accV[s][2][tp][r] * f;
        }
      }
    }
  }
}

extern "C" void kernel_launch(void* const* d_in, const int* in_sizes, int n_in,
                              void* d_out, int out_size, void* d_ws, size_t ws_size,
                              hipStream_t stream) {
  (void)in_sizes; (void)n_in; (void)out_size; (void)ws_size;
  const float* fea1 = (const float*)d_in[0];
  const float* fea2 = (const float*)d_in[1];
  const float* few  = (const float*)d_in[2];
  unsigned short* wsb = (unsigned short*)d_ws;

  prep_weights<<<(WS_TOTAL + 255)/256, 256, 0, stream>>>(
      (const float*)d_in[3], (const float*)d_in[4],
      (const float*)d_in[5], (const float*)d_in[6],
      (const float*)d_in[7], (const float*)d_in[8],
      (const float*)d_in[9], (const float*)d_in[11], (const float*)d_in[13],
      wsb);

  equiconv_main<<<(E_TOT + 127)/128, 256, 0, stream>>>(
      fea1, fea2, few,
      (const float*)d_in[10], (const float*)d_in[12], (const float*)d_in[14],
      (const unsigned short*)wsb, (float*)d_out);
}

// Round 6
// 181.038 us; speedup vs baseline: 5.1243x; 5.1243x over previous
//
#include <hip/hip_runtime.h>

// EquiConv fused MFMA kernel for MI355X (gfx950) — round 6.
// R5 + ring read/overwrite fix: with a 2-slot ring, chunk c+2 lands in the SAME
// slot READ6(c) reads. ds_read issue order alone doesn't guarantee the reads
// sample LDS before the DMA write arrives (~200-600cyc later). Fix: s_waitcnt
// lgkmcnt(0) + sched_barrier between READ6(c) and issue(c+2) — reads are
// retired into VGPRs before the overwriting DMA is issued (timing-independent).
// Tail chunk keeps vmcnt(0) (R5 fix). All mappings audited line-by-line.
// Design: wave-private 52x6KB stream, 2-slot ring/wave, depth-2 prefetch,
// no __syncthreads in K-loop; T=2 M-tiles/wave; grid 625x4; ~68KB LDS ->
// 2 blocks/CU. Fragment layouts per learn_hip m89/m120.

#define E_TOT 20000

typedef __attribute__((ext_vector_type(8))) short short8;
typedef __attribute__((ext_vector_type(4))) float f32x4;
typedef __attribute__((ext_vector_type(2))) __bf16 bf16x2;

#define FRAG_USH 512
#define CH_USH   3072          // 6 frags = 6KB
#define N_CH     52
#define STRIDE_W 159744        // 312 frags * 512 ushort per wave stream
#define FC1_OFF  638976        // 4*STRIDE_W
#define FC2_OFF  647168
#define FC3_OFF  651264
#define WS_USH   657408        // 1.28 MB of d_ws

// src array sizes / cumulative offsets (prep thread = one src element)
#define S_SSS 262144
#define O_SSG (S_SSS)          // 262144
#define O_VVS (O_SSG+131072)   // 393216
#define O_VVG (O_VVS+65536)    // 458752
#define O_SV  (O_VVG+32768)    // 491520
#define O_VS  (O_SV+65536)     // 557056
#define O_F1  (O_VS+65536)     // 622592
#define O_F2  (O_F1+8192)      // 630784
#define O_F3  (O_F2+4096)      // 634880
#define N_SRC (O_F3+6144)      // 641024

__device__ __forceinline__ unsigned short f2b(float f){
  return __builtin_bit_cast(unsigned short, (__bf16)f);
}
__device__ __forceinline__ unsigned f2b2(float lo, float hi){
  bf16x2 t; t[0] = (__bf16)lo; t[1] = (__bf16)hi;
  return __builtin_bit_cast(unsigned, t);
}
__device__ __forceinline__ float b2f(unsigned short h){
  return __uint_as_float(((unsigned)h) << 16);
}
__device__ __forceinline__ f32x4 mfma16(short8 a, short8 b, f32x4 c){
  return __builtin_amdgcn_mfma_f32_16x16x32_bf16(a, b, c, 0, 0, 0);
}
union U8 { short8 v; unsigned u[4]; };
__device__ __forceinline__ float silu_f(float x){ return x/(1.f+__expf(-x)); }
__device__ __forceinline__ float sigm_f(float x){ return 1.f/(1.f+__expf(-x)); }

#define PACK8(a, s, x) \
  a.u[0]=f2b2((s)*(x)[0],(s)*(x)[1]); a.u[1]=f2b2((s)*(x)[2],(s)*(x)[3]); \
  a.u[2]=f2b2((s)*(x)[4],(s)*(x)[5]); a.u[3]=f2b2((s)*(x)[6],(s)*(x)[7]);

// s_waitcnt encodings (gfx9 simm16: vmcnt[3:0]|[15:14], expcnt[6:4], lgkmcnt[11:8])
#define WAITV6 { __builtin_amdgcn_s_waitcnt(0xF76);  __builtin_amdgcn_sched_barrier(0); }
#define WAITV0 { __builtin_amdgcn_s_waitcnt(0xF70);  __builtin_amdgcn_sched_barrier(0); }
#define WAITL0 { __builtin_amdgcn_s_waitcnt(0xC07F); __builtin_amdgcn_sched_barrier(0); }

// dest position of (k_local, n16) inside a 512-ushort fragment
__device__ __forceinline__ int fpos(int kl, int n16){
  return (kl>>3)*128 + n16*8 + (kl&7);
}

// ---------------- prep: src-linear scatter into per-wave streams ----------------
__global__ void prep_weights(const float* __restrict__ ss_s, const float* __restrict__ ss_g,
                             const float* __restrict__ vv_s, const float* __restrict__ vv_g,
                             const float* __restrict__ sv,   const float* __restrict__ vs,
                             const float* __restrict__ w1,   const float* __restrict__ w2,
                             const float* __restrict__ w3,   unsigned short* __restrict__ wsb)
{
  int idx = blockIdx.x * 256 + threadIdx.x;
  if (idx >= N_SRC) return;
  const float A_SC  = 0.013975424859373686f;                     // 1/sqrt(S*S+V*V)
  const float A_VV  = (float)(0.013975424859373686 * 0.5773502691896258);
  const float A_VEC = 0.015625f;                                 // 1/sqrt(2*S*V)
  float val; int dest;
  if (idx < O_SSG){                         // ss_s [64][64][64] -> SS chunks 0..31
    int i = idx;
    int u = i >> 12, v = (i >> 6) & 63, w = i & 63;
    int wave = u >> 4, ul = u & 15;
    dest = wave*STRIDE_W + (ul*2 + (v>>5))*CH_USH + (w>>4)*FRAG_USH + fpos(v&31, w&15);
    val = A_SC * ss_s[i];
  } else if (idx < O_VVS){                  // ss_g [64][64][32] -> SS frags t=4,5
    int i = idx - O_SSG;
    int u = i >> 11, v = (i >> 5) & 63, w = i & 31;
    int wave = u >> 4, ul = u & 15;
    dest = wave*STRIDE_W + (ul*2 + (v>>5))*CH_USH + (4+(w>>4))*FRAG_USH + fpos(v&31, w&15);
    val = A_SC * ss_g[i];
  } else if (idx < O_VVG){                  // vv_s [32][32][64] -> VV chunks 32..39
    int i = idx - O_VVS;
    int u = i >> 11, v = (i >> 6) & 31, w = i & 63;
    int wave = u >> 3, ul = u & 7;
    dest = wave*STRIDE_W + (32+ul)*CH_USH + (w>>4)*FRAG_USH + fpos(v, w&15);
    val = A_VV * vv_s[i];
  } else if (idx < O_SV){                   // vv_g [32][32][32] -> VV frags t=4,5
    int i = idx - O_VVG;
    int u = i >> 10, v = (i >> 5) & 31, w = i & 31;
    int wave = u >> 3, ul = u & 7;
    dest = wave*STRIDE_W + (32+ul)*CH_USH + (4+(w>>4))*FRAG_USH + fpos(v, w&15);
    val = A_VV * vv_g[i];
  } else if (idx < O_VS){                   // sv [64][32][32] -> chunks 40..45
    int i = idx - O_SV;
    int u = i >> 10, v = (i >> 5) & 31, w = i & 31;
    int wave = u >> 4, ul = u & 15;
    dest = wave*STRIDE_W + (40 + ul/3)*CH_USH + ((ul%3)*2 + (w>>4))*FRAG_USH + fpos(v, w&15);
    val = A_VEC * sv[i];
  } else if (idx < O_F1){                   // vs [32][64][32] -> chunks 46..51
    int i = idx - O_VS;
    int u = i >> 11, v = (i >> 5) & 63, w = i & 31;
    int wave = u >> 3, ul = u & 7;
    int fseq = ul*2 + (w>>4);
    dest = wave*STRIDE_W + (46 + (v>>5)*3 + fseq/6)*CH_USH + (fseq%6)*FRAG_USH + fpos(v&31, w&15);
    val = A_VEC * vs[i];
  } else if (idx < O_F2){                   // fc1 [128][64]
    int i = idx - O_F1;
    int k = i >> 6, n = i & 63;
    dest = FC1_OFF + ((k>>5)*4 + (n>>4))*FRAG_USH + fpos(k&31, n&15);
    val = w1[i];
  } else if (idx < O_F3){                   // fc2 [64][64]
    int i = idx - O_F2;
    int k = i >> 6, n = i & 63;
    dest = FC2_OFF + ((k>>5)*4 + (n>>4))*FRAG_USH + fpos(k&31, n&15);
    val = w2[i];
  } else {                                  // fc3 [64][96]
    int i = idx - O_F3;
    int k = i / 96, n = i - k*96;
    dest = FC3_OFF + ((k>>5)*6 + (n>>4))*FRAG_USH + fpos(k&31, n&15);
    val = w3[i];
  }
  wsb[dest] = f2b(val);
}

// ---------------- main fused kernel ----------------
__global__ __launch_bounds__(256, 2)
void equiconv_main(const float* __restrict__ fea1,
                   const float* __restrict__ fea2,
                   const float* __restrict__ few,
                   const float* __restrict__ fb1,
                   const float* __restrict__ fb2,
                   const float* __restrict__ fb3,
                   const unsigned short* __restrict__ wsb,
                   float* __restrict__ out)
{
  __shared__ __align__(16) unsigned short ring[4*2*CH_USH];  // 48 KB; reused as red
  __shared__ __align__(16) unsigned short x1s[32][66];
  __shared__ __align__(16) unsigned short x1v[32][98];
  __shared__ __align__(16) unsigned short hb[4][16][72];

  const int tid  = threadIdx.x;
  const int lane = tid & 63, wv = tid >> 6;
  const int ln   = lane & 15, quad = lane >> 4, q8 = quad << 3;
  const int ebase = blockIdx.x << 5;          // 625 * 32 == 20000 exactly

  // ---- stage x1 (32 edges) into LDS as bf16 ----
  for (int it = tid; it < 1280; it += 256){
    int row = it / 40, seg = it - row*40;
    float4 v1 = *(const float4*)(fea1 + (size_t)(ebase + row)*160 + seg*4);
    const float* p1 = (const float*)&v1;
    int c0 = seg*4;
    #pragma unroll
    for (int jj = 0; jj < 4; jj++){
      int col = c0 + jj;
      if (col < 64) x1s[row][col] = f2b(p1[jj]);
      else          x1v[row][col-64] = f2b(p1[jj]);
    }
  }
  __syncthreads();

  // ---- hoist per-lane x2 fragments for both sub-tiles (direct from global) ----
  float xe[2][8], xo[2][8], y0[2][8], y1[2][8], y2[2][8];
  #pragma unroll
  for (int s = 0; s < 2; s++){
    const float* p = fea2 + (size_t)(ebase + s*16 + ln)*160;
    float4 a0 = *(const float4*)(p + q8);
    float4 a1 = *(const float4*)(p + q8 + 4);
    float4 b0 = *(const float4*)(p + 32 + q8);
    float4 b1 = *(const float4*)(p + 36 + q8);
    xe[s][0]=a0.x; xe[s][1]=a0.y; xe[s][2]=a0.z; xe[s][3]=a0.w;
    xe[s][4]=a1.x; xe[s][5]=a1.y; xe[s][6]=a1.z; xe[s][7]=a1.w;
    xo[s][0]=b0.x; xo[s][1]=b0.y; xo[s][2]=b0.z; xo[s][3]=b0.w;
    xo[s][4]=b1.x; xo[s][5]=b1.y; xo[s][6]=b1.z; xo[s][7]=b1.w;
    const float* py = p + 64 + q8*3;
    float yb[24];
    #pragma unroll
    for (int t = 0; t < 12; t++){
      float2 f2v = *(const float2*)(py + 2*t);
      yb[2*t] = f2v.x; yb[2*t+1] = f2v.y;
    }
    #pragma unroll
    for (int j = 0; j < 8; j++){
      y0[s][j] = yb[3*j]; y1[s][j] = yb[3*j+1]; y2[s][j] = yb[3*j+2];
    }
  }

  // ---- wave-private ring machinery ----
  const unsigned short* gstream = wsb + (size_t)wv*STRIDE_W;
  const int rbase = wv*2*CH_USH;              // ushort offset of this wave's 2 slots
  auto issue_chunk = [&](int c){
    const unsigned short* g = gstream + c*CH_USH + lane*8;
    unsigned short* l = &ring[rbase + (c&1)*CH_USH];
    #pragma unroll
    for (int q = 0; q < 6; q++)
      __builtin_amdgcn_global_load_lds(
        (const __attribute__((address_space(1))) unsigned int*)(g + q*FRAG_USH),
        (__attribute__((address_space(3))) unsigned int*)(l + q*FRAG_USH),
        16, 0, 0);
  };
  issue_chunk(0); issue_chunk(1);             // prime: 12 outstanding

  const int r0 = ln, r1 = 16 + ln;            // x1 rows for sub0/sub1
  const f32x4 z4 = {0.f,0.f,0.f,0.f};
  f32x4 accS[2][6] = {{z4,z4,z4,z4,z4,z4},{z4,z4,z4,z4,z4,z4}};
  f32x4 accV[2][3][2] = {{{z4,z4},{z4,z4},{z4,z4}},{{z4,z4},{z4,z4},{z4,z4}}};

  #define READ6(c, bb) { \
    const unsigned short* sl = &ring[rbase + ((c)&1)*CH_USH + lane*8]; \
    _Pragma("unroll") for (int t = 0; t < 6; t++) bb[t] = *(const short8*)(sl + t*FRAG_USH); }
  // lgkmcnt(0): READ6(c)'s ds_reads retired into VGPRs BEFORE the DMA that
  // overwrites slot c&1 (chunk c+2) is issued — timing-independent (R5 fix).
  #define STEP(c) { WAITL0; if ((c)+2 < N_CH) issue_chunk((c)+2); }

  // ===== SS: chunks 0..31; c = 2*u16 + half =====
  #pragma unroll 2
  for (int c = 0; c < 32; c++){
    int u = (wv<<4) + (c>>1);
    float s0 = b2f(x1s[r0][u]);
    float s1 = b2f(x1s[r1][u]);
    WAITV6;
    short8 bb[6]; READ6(c, bb); STEP(c);
    U8 a0, a1;
    if (c & 1){ PACK8(a0, s0, xo[0]); PACK8(a1, s1, xo[1]); }
    else      { PACK8(a0, s0, xe[0]); PACK8(a1, s1, xe[1]); }
    #pragma unroll
    for (int t = 0; t < 6; t++){
      accS[0][t] = mfma16(a0.v, bb[t], accS[0][t]);
      accS[1][t] = mfma16(a1.v, bb[t], accS[1][t]);
    }
  }
  // ===== VV: chunks 32..39; one u per chunk =====
  #pragma unroll 1
  for (int k8 = 0; k8 < 8; k8++){
    int c = 32 + k8, u = (wv<<3) + k8;
    U8 a[2];
    #pragma unroll
    for (int s = 0; s < 2; s++){
      int rr = s ? r1 : r0;
      float c0 = b2f(x1v[rr][u*3+0]);
      float c1 = b2f(x1v[rr][u*3+1]);
      float c2 = b2f(x1v[rr][u*3+2]);
      float pv[8];
      #pragma unroll
      for (int j = 0; j < 8; j++)
        pv[j] = c0*y0[s][j] + c1*y1[s][j] + c2*y2[s][j];
      a[s].u[0]=f2b2(pv[0],pv[1]); a[s].u[1]=f2b2(pv[2],pv[3]);
      a[s].u[2]=f2b2(pv[4],pv[5]); a[s].u[3]=f2b2(pv[6],pv[7]);
    }
    WAITV6;
    short8 bb[6]; READ6(c, bb); STEP(c);
    #pragma unroll
    for (int t = 0; t < 6; t++){
      accS[0][t] = mfma16(a[0].v, bb[t], accS[0][t]);
      accS[1][t] = mfma16(a[1].v, bb[t], accS[1][t]);
    }
  }
  // ===== SV: chunks 40..45; 3 u per chunk, 2 frags each =====
  #pragma unroll 1
  for (int ch = 0; ch < 6; ch++){
    int c = 40 + ch;
    WAITV6;
    short8 bb[6]; READ6(c, bb); STEP(c);
    #pragma unroll
    for (int uu = 0; uu < 3; uu++){
      int ui = ch*3 + uu;
      if (ui < 16){
        int u = (wv<<4) + ui;
        float s0 = b2f(x1s[r0][u]);
        float s1 = b2f(x1s[r1][u]);
        U8 a[2][3];
        PACK8(a[0][0], s0, y0[0]); PACK8(a[0][1], s0, y1[0]); PACK8(a[0][2], s0, y2[0]);
        PACK8(a[1][0], s1, y0[1]); PACK8(a[1][1], s1, y1[1]); PACK8(a[1][2], s1, y2[1]);
        #pragma unroll
        for (int t = 0; t < 2; t++){
          short8 b8 = bb[uu*2 + t];
          #pragma unroll
          for (int s = 0; s < 2; s++)
            #pragma unroll
            for (int i = 0; i < 3; i++)
              accV[s][i][t] = mfma16(a[s][i].v, b8, accV[s][i][t]);
        }
      }
    }
  }
  // ===== VS: chunks 46..51; phase p (xe/xo), 3 u per chunk, 2 frags each =====
  #pragma unroll 1
  for (int pc = 0; pc < 6; pc++){
    int p = pc / 3, ch = pc - p*3;
    int c = 46 + pc;
    if (pc < 5) { WAITV6 }     // mid-stream: c and c+1 in flight -> drains c
    else        { WAITV0 }     // tail: only c's 6 loads outstanding (R5 fix)
    short8 bb[6]; READ6(c, bb); STEP(c);
    #pragma unroll
    for (int uu = 0; uu < 3; uu++){
      int ui = ch*3 + uu;
      if (ui < 8){
        int u = (wv<<3) + ui;
        U8 a[2][3];
        #pragma unroll
        for (int s = 0; s < 2; s++){
          int rr = s ? r1 : r0;
          float c0 = b2f(x1v[rr][u*3+0]);
          float c1 = b2f(x1v[rr][u*3+1]);
          float c2 = b2f(x1v[rr][u*3+2]);
          const float* xx = p ? xo[s] : xe[s];
          PACK8(a[s][0], c0, xx); PACK8(a[s][1], c1, xx); PACK8(a[s][2], c2, xx);
        }
        #pragma unroll
        for (int t = 0; t < 2; t++){
          short8 b8 = bb[uu*2 + t];
          #pragma unroll
          for (int s = 0; s < 2; s++)
            #pragma unroll
            for (int i = 0; i < 3; i++)
              accV[s][i][t] = mfma16(a[s][i].v, b8, accV[s][i][t]);
        }
      }
    }
  }

  // ---- gather partials: T0 = sub0's 12 tiles, T1 = sub1's ----
  f32x4 T0[12], T1[12];
  #pragma unroll
  for (int t = 0; t < 6; t++){ T0[t] = accS[0][t]; T1[t] = accS[1][t]; }
  #pragma unroll
  for (int t = 0; t < 2; t++)
    #pragma unroll
    for (int i = 0; i < 3; i++){
      T0[6+3*t+i] = accV[0][i][t]; T1[6+3*t+i] = accV[1][i][t];
    }

  // ---- cross-wave K-reduction through reused ring (A=slots0-11, B=12-23) ----
  float* redf = (float*)ring;
  #define PUT12(base, T) { _Pragma("unroll") for (int j=0;j<12;j++) \
    *(f32x4*)(redf + ((base)+j)*320 + ln*20 + (quad<<2)) = T[j]; }
  #define ADD12(base, T) { _Pragma("unroll") for (int j=0;j<12;j++) \
    T[j] += *(const f32x4*)(redf + ((base)+j)*320 + ln*20 + (quad<<2)); }

  __syncthreads();                               // all waves drained own DMA (WAITV0)
  if (wv==1) PUT12(0, T0);  if (wv==2) PUT12(12, T1);
  __syncthreads();
  if (wv==0) ADD12(0, T0);  if (wv==3) ADD12(12, T1);
  __syncthreads();
  if (wv==2) PUT12(0, T0);  if (wv==1) PUT12(12, T1);
  __syncthreads();
  if (wv==0) ADD12(0, T0);  if (wv==3) ADD12(12, T1);
  __syncthreads();
  if (wv==3) PUT12(0, T0);  if (wv==0) PUT12(12, T1);
  __syncthreads();
  if (wv==0) ADD12(0, T0);  if (wv==3) ADD12(12, T1);
  // w0 now owns final sub0 tiles in T0; w3 owns final sub1 in T1.

  if (wv == 1 || wv == 2) return;
  const int s = (wv == 0) ? 0 : 1;
  f32x4* P = (wv == 0) ? T0 : T1;

  // ---- FC chain (owner wave, wave-private h buffer) ----
  f32x4 accF[4] = {z4,z4,z4,z4};
  {
    const float* fwp = few + (size_t)(ebase + s*16 + ln)*128;
    const short8* B = (const short8*)(wsb + FC1_OFF);
    #pragma unroll
    for (int c = 0; c < 4; c++){
      float4 fa  = *(const float4*)(fwp + c*32 + q8);
      float4 fbv = *(const float4*)(fwp + c*32 + q8 + 4);
      U8 a;
      a.u[0]=f2b2(fa.x,fa.y);   a.u[1]=f2b2(fa.z,fa.w);
      a.u[2]=f2b2(fbv.x,fbv.y); a.u[3]=f2b2(fbv.z,fbv.w);
      #pragma unroll
      for (int t = 0; t < 4; t++) accF[t] = mfma16(a.v, B[(c*4+t)*64 + lane], accF[t]);
    }
  }
  #pragma unroll
  for (int t = 0; t < 4; t++){
    float bb = fb1[(t<<4)+ln];
    #pragma unroll
    for (int r = 0; r < 4; r++)
      hb[wv][(quad<<2)+r][(t<<4)+ln] = f2b(silu_f(accF[t][r] + bb));
  }
  f32x4 acc2[4] = {z4,z4,z4,z4};
  {
    const short8* B = (const short8*)(wsb + FC2_OFF);
    #pragma unroll
    for (int c = 0; c < 2; c++){
      uint4 hq = *(const uint4*)&hb[wv][ln][c*32 + q8];
      U8 a; a.u[0]=hq.x; a.u[1]=hq.y; a.u[2]=hq.z; a.u[3]=hq.w;
      #pragma unroll
      for (int t = 0; t < 4; t++) acc2[t] = mfma16(a.v, B[(c*4+t)*64 + lane], acc2[t]);
    }
  }
  #pragma unroll
  for (int t = 0; t < 4; t++){
    float bb = fb2[(t<<4)+ln];
    #pragma unroll
    for (int r = 0; r < 4; r++)
      hb[wv][(quad<<2)+r][(t<<4)+ln] = f2b(silu_f(acc2[t][r] + bb));
  }
  f32x4 acc3[6] = {z4,z4,z4,z4,z4,z4};
  {
    const short8* B = (const short8*)(wsb + FC3_OFF);
    #pragma unroll
    for (int c = 0; c < 2; c++){
      uint4 hq = *(const uint4*)&hb[wv][ln][c*32 + q8];
      U8 a; a.u[0]=hq.x; a.u[1]=hq.y; a.u[2]=hq.z; a.u[3]=hq.w;
      #pragma unroll
      for (int t = 0; t < 6; t++) acc3[t] = mfma16(a.v, B[(c*6+t)*64 + lane], acc3[t]);
    }
  }

  // ---- epilogue (C-layout row = quad*4+r; 625*32 = 20000, no guards) ----
  #pragma unroll
  for (int r = 0; r < 4; r++){
    int eg = ebase + s*16 + (quad<<2) + r;
    float* op = out + (size_t)eg*160;
    #pragma unroll
    for (int t = 0; t < 4; t++)
      op[(t<<4)+ln] = silu_f(P[t][r]) * (acc3[t][r] + fb3[(t<<4)+ln]);
    #pragma unroll
    for (int tp = 0; tp < 2; tp++){
      int wc = (tp<<4) + ln;
      float f = sigm_f(P[4+tp][r]) * (acc3[4+tp][r] + fb3[64+wc]);
      op[64 + wc*3 + 0] = P[6+3*tp+0][r] * f;
      op[64 + wc*3 + 1] = P[6+3*tp+1][r] * f;
      op[64 + wc*3 + 2] = P[6+3*tp+2][r] * f;
    }
  }
}

extern "C" void kernel_launch(void* const* d_in, const int* in_sizes, int n_in,
                              void* d_out, int out_size, void* d_ws, size_t ws_size,
                              hipStream_t stream) {
  (void)in_sizes; (void)n_in; (void)out_size; (void)ws_size;
  unsigned short* wsb = (unsigned short*)d_ws;

  prep_weights<<<(N_SRC + 255)/256, 256, 0, stream>>>(
      (const float*)d_in[3], (const float*)d_in[5],     // ss_s, ss_g
      (const float*)d_in[4], (const float*)d_in[6],     // vv_s, vv_g
      (const float*)d_in[7], (const float*)d_in[8],     // sv, vs
      (const float*)d_in[9], (const float*)d_in[11], (const float*)d_in[13],
      wsb);

  equiconv_main<<<E_TOT/32, 256, 0, stream>>>(
      (const float*)d_in[0], (const float*)d_in[1], (const float*)d_in[2],
      (const float*)d_in[10], (const float*)d_in[12], (const float*)d_in[14],
      (const unsigned short*)wsb, (float*)d_out);
}